// Round 2
// baseline (6128.997 us; speedup 1.0000x reference)
//
#include <hip/hip_runtime.h>
#include <stdint.h>

// BiLevelRoutingAttention (spiking LIF), T=4 B=2 L=8x32x32 C=256, fp32 I/O.
#define NT 4
#define NB 2
#define NW 32   // windows = 2*4*4
#define NS 256  // tokens/window = 4*8*8
#define NC 256
#define NH 8
#define ND 32
#define NK 4    // topk

typedef unsigned int u32;

// window/space mapping:
//   w = wt*16 + wh*4 + ww ; s = it*64 + ih*8 + iw
//   Lt = wt*4+it, Lh = wh*8+ih, Lw = ww*8+iw
__device__ __forceinline__ size_t x_off(int t, int b, int w, int s, int c) {
  int wt = w >> 4, wh = (w >> 2) & 3, ww = w & 3;
  int it = s >> 6, ih = (s >> 3) & 7, iw = s & 7;
  return ((((size_t)(t * NB + b) * 8 + (wt * 4 + it)) * 32 + (wh * 8 + ih)) * 32 + (ww * 8 + iw)) * NC + c;
}

// K1: partial region sums: partial[((t*NB+b)*NW+w)*NC + c] = sum over s of x
__global__ __launch_bounds__(256) void k_region(const float* __restrict__ x,
                                                float* __restrict__ partial) {
  int blk = blockIdx.x;  // 256 = ((t*NB+b)*NW+w)
  int t = blk >> 6, b = (blk >> 5) & 1, w = blk & 31;
  int c = threadIdx.x;
  float sum = 0.f;
  for (int s = 0; s < NS; ++s) sum += x[x_off(t, b, w, s, c)];
  partial[(size_t)blk * NC + c] = sum;
}

// K2: reduce partials -> region mean, scores, top-4 (ties -> lower index)
__global__ __launch_bounds__(256) void k_topk(const float* __restrict__ partial,
                                              int* __restrict__ idx) {
  __shared__ float rs[NB * NW * NC];  // 64 KB
  int tid = threadIdx.x;
  for (int i = tid; i < NB * NW * NC; i += 256) {
    float s = 0.f;
    for (int t = 0; t < NT; ++t) s += partial[(size_t)t * NB * NW * NC + i];
    rs[i] = s * (1.0f / 1024.0f);
  }
  __syncthreads();
  if (tid < NB * NW) {
    int b = tid >> 5, w = tid & 31;
    const float scale = 0.17677669529663687f;  // 32^-0.5
    float sc[NW];
    for (int v = 0; v < NW; ++v) {
      float s = 0.f;
      const float* a = &rs[(b * NW + w) * NC];
      const float* bb = &rs[(b * NW + v) * NC];
      for (int c = 0; c < NC; ++c) s += a[c] * bb[c];
      sc[v] = s * scale;
    }
    for (int kk = 0; kk < NK; ++kk) {
      float best = -__builtin_inff(); int bi = 0;
      for (int v = 0; v < NW; ++v)
        if (sc[v] > best) { best = sc[v]; bi = v; }
      idx[(b * NW + w) * NK + kk] = bi;
      sc[bi] = -__builtin_inff();
    }
  }
}

// K3: qkv = x @ w_qkv + b_qkv ; spike = (qkv >= 2.0)  [LIF: x/2 - 1 >= 0]
// spikes stored as bitmasks: {q,k,v}b[token*8 + h], bit d
__global__ __launch_bounds__(256) void k_qkv(const float* __restrict__ x,
                                             const float* __restrict__ w_qkv,
                                             const float* __restrict__ b_qkv,
                                             u32* __restrict__ qb, u32* __restrict__ kb,
                                             u32* __restrict__ vb) {
  __shared__ float xs[32][257];
  int tid = threadIdx.x;
  int tok0 = blockIdx.x * 32;
  // stage 32 token rows (float4), gathered through window mapping
  for (int i = tid; i < 32 * 64; i += 256) {
    int r = i >> 6, c4 = i & 63;
    int g = tok0 + r;
    int s = g & 255, w = (g >> 8) & 31, tb = g >> 13;  // token = ((t*NB+b)*NW+w)*NS+s
    int b = tb & 1, t = tb >> 1;
    float4 v = *reinterpret_cast<const float4*>(&x[x_off(t, b, w, s, c4 * 4)]);
    xs[r][c4 * 4 + 0] = v.x;
    xs[r][c4 * 4 + 1] = v.y;
    xs[r][c4 * 4 + 2] = v.z;
    xs[r][c4 * 4 + 3] = v.w;
  }
  __syncthreads();
  for (int widx = tid; widx < 768; widx += 256) {  // 32 tokens * 24 slots
    int i = widx / 24;
    int slot = widx % 24;  // 0..7 q, 8..15 k, 16..23 v
    int j0 = slot * 32;
    float acc[32];
#pragma unroll
    for (int j = 0; j < 32; ++j) acc[j] = b_qkv[j0 + j];
    for (int k = 0; k < 256; ++k) {
      float xv = xs[i][k];
      const float4* wp = reinterpret_cast<const float4*>(w_qkv + (size_t)k * 768 + j0);
#pragma unroll
      for (int g4 = 0; g4 < 8; ++g4) {
        float4 u = wp[g4];
        acc[g4 * 4 + 0] += xv * u.x;
        acc[g4 * 4 + 1] += xv * u.y;
        acc[g4 * 4 + 2] += xv * u.z;
        acc[g4 * 4 + 3] += xv * u.w;
      }
    }
    u32 word = 0;
#pragma unroll
    for (int j = 0; j < 32; ++j) word |= (acc[j] >= 2.0f ? 1u : 0u) << j;
    int which = slot >> 3, h = slot & 7;
    u32* dst = (which == 0) ? qb : (which == 1) ? kb : vb;
    dst[(size_t)(tok0 + i) * NH + h] = word;
  }
}

// K4: fused gather + linear attention + proj + window reverse.
// Fast path: no q spikes OR no gathered (k&v) co-spike -> attention == 0 -> out = b_proj.
__global__ __launch_bounds__(256) void k_attn(const u32* __restrict__ qb,
                                              const u32* __restrict__ kb,
                                              const u32* __restrict__ vb,
                                              const int* __restrict__ idx,
                                              const float* __restrict__ w_proj,
                                              const float* __restrict__ b_proj,
                                              float* __restrict__ out) {
  __shared__ u32 qs[NS * NH];            // 8 KB
  __shared__ unsigned short kvc[NH * ND * ND];  // 16 KB
  __shared__ u32 ksum[NH * ND];          // 1 KB
  __shared__ float attnrow[NC];
  __shared__ size_t gbase[NK];
  __shared__ u32 flags[2];

  int blk = blockIdx.x;  // 256 = t*64 + b*32 + w
  int t = blk >> 6, b = (blk >> 5) & 1, w = blk & 31;
  int tid = threadIdx.x;
  if (tid < 2) flags[tid] = 0;
  if (tid < NK) {
    int wj = idx[(b * NW + w) * NK + tid];
    gbase[tid] = ((size_t)((t * NB + b) * NW + wj)) * NS * NH;
  }
  size_t qbase = ((size_t)((t * NB + b) * NW + w)) * NS * NH;
  u32 myq = 0;
  for (int i = tid; i < NS * NH; i += 256) { u32 u = qb[qbase + i]; qs[i] = u; myq |= u; }
  __syncthreads();
  u32 mykv = 0;
  for (int i = tid; i < NK * NS * NH; i += 256) {
    int j = i >> 11, r = i & 2047;
    u32 ku = kb[gbase[j] + r], vu = vb[gbase[j] + r];
    if (ku && vu) mykv = 1;
  }
  if (myq) atomicOr(&flags[0], 1u);
  if (mykv) atomicOr(&flags[1], 1u);
  __syncthreads();
  bool skip = (flags[0] == 0) || (flags[1] == 0);

  if (skip) {
    float bp = b_proj[tid];
    for (int s = 0; s < NS; ++s) out[x_off(t, b, w, s, tid)] = bp;
    return;
  }

  // ---- slow path (exact integer attention), taken only if spikes exist ----
  {
    int h = tid >> 5, d = tid & 31;
    u32 cnt = 0;
    for (int n = 0; n < NK * NS; ++n)
      cnt += (kb[gbase[n >> 8] + (n & 255) * NH + h] >> d) & 1u;
    ksum[tid] = cnt;
  }
  for (int p = tid; p < NH * ND * ND; p += 256) {
    int h = p >> 10, d = (p >> 5) & 31, e = p & 31;
    u32 cnt = 0;
    for (int n = 0; n < NK * NS; ++n) {
      u32 ku = kb[gbase[n >> 8] + (n & 255) * NH + h];
      u32 vu = vb[gbase[n >> 8] + (n & 255) * NH + h];
      cnt += ((ku >> d) & (vu >> e)) & 1u;
    }
    kvc[p] = (unsigned short)cnt;
  }
  __syncthreads();
  int h = tid >> 5, e = tid & 31;
  float bpv = b_proj[tid];
  for (int s = 0; s < NS; ++s) {
    u32 qw = qs[s * NH + h];
    float num = 0.f, den = 0.f;
    for (int d = 0; d < ND; ++d) {
      if ((qw >> d) & 1u) {
        den += (float)ksum[h * ND + d];
        num += (float)kvc[h * ND * ND + d * ND + e];
      }
    }
    attnrow[tid] = num / (den + 1e-6f);
    __syncthreads();
    float acc = bpv;
    for (int c = 0; c < NC; ++c) acc += attnrow[c] * w_proj[c * NC + tid];
    out[x_off(t, b, w, s, tid)] = acc;
    __syncthreads();
  }
}

extern "C" void kernel_launch(void* const* d_in, const int* in_sizes, int n_in,
                              void* d_out, int out_size, void* d_ws, size_t ws_size,
                              hipStream_t stream) {
  const float* x      = (const float*)d_in[0];
  const float* w_qkv  = (const float*)d_in[1];
  const float* b_qkv  = (const float*)d_in[2];
  const float* w_proj = (const float*)d_in[3];
  const float* b_proj = (const float*)d_in[4];
  float* out = (float*)d_out;

  char* ws = (char*)d_ws;
  float* partial = (float*)ws;                 // 256 KB: [t][b][w][c] sums
  int* idx       = (int*)(ws + (1 << 18));     // 1 KB
  u32* qb        = (u32*)(ws + (1 << 20));     // 2 MB each
  u32* kb        = qb + (size_t)NT * NB * NW * NS * NH;
  u32* vb        = kb + (size_t)NT * NB * NW * NS * NH;

  k_region<<<NT * NB * NW, 256, 0, stream>>>(x, partial);
  k_topk<<<1, 256, 0, stream>>>(partial, idx);
  k_qkv<<<(NT * NB * NW * NS) / 32, 256, 0, stream>>>(x, w_qkv, b_qkv, qb, kb, vb);
  k_attn<<<NT * NB * NW, 256, 0, stream>>>(qb, kb, vb, idx, w_proj, b_proj, out);
}

// Round 4
// 232.127 us; speedup vs baseline: 26.4036x; 26.4036x over previous
//
#include <hip/hip_runtime.h>
#include <hip/hip_bf16.h>
#include <stdint.h>

// BiLevelRoutingAttention (spiking LIF), T=4 B=2 L=8x32x32 C=256, fp32 I/O.
#define NT 4
#define NB 2
#define NW 32   // windows = 2*4*4
#define NS 256  // tokens/window = 4*8*8
#define NC 256
#define NH 8
#define ND 32
#define NK 4    // topk

typedef unsigned int u32;
typedef unsigned short u16;
typedef __attribute__((ext_vector_type(8))) short bf16x8;   // 8 bf16 (4 VGPRs)
typedef __attribute__((ext_vector_type(8))) unsigned short u16x8;
typedef __attribute__((ext_vector_type(4))) float f32x4;

// window/space mapping:
//   w = wt*16 + wh*4 + ww ; s = it*64 + ih*8 + iw
//   Lt = wt*4+it, Lh = wh*8+ih, Lw = ww*8+iw
__device__ __forceinline__ size_t x_off(int t, int b, int w, int s, int c) {
  int wt = w >> 4, wh = (w >> 2) & 3, ww = w & 3;
  int it = s >> 6, ih = (s >> 3) & 7, iw = s & 7;
  return ((((size_t)(t * NB + b) * 8 + (wt * 4 + it)) * 32 + (wh * 8 + ih)) * 32 + (ww * 8 + iw)) * NC + c;
}

// fp32 -> bf16 round-to-nearest-even (self-contained)
__device__ __forceinline__ u16 f2bf(float f) {
  union { float f; u32 i; } u; u.f = f;
  u32 r = (u.i + 0x7FFFu + ((u.i >> 16) & 1u)) >> 16;
  return (u16)r;
}

// K1: partial region sums: partial[((t*NB+b)*NW+w)*NC + c] = sum over s of x
__global__ __launch_bounds__(256) void k_region(const float* __restrict__ x,
                                                float* __restrict__ partial) {
  int blk = blockIdx.x;  // 256 = ((t*NB+b)*NW+w)
  int t = blk >> 6, b = (blk >> 5) & 1, w = blk & 31;
  int c = threadIdx.x;
  float sum = 0.f;
  for (int s = 0; s < NS; ++s) sum += x[x_off(t, b, w, s, c)];
  partial[(size_t)blk * NC + c] = sum;
}

// K2: w_qkv [256][768] fp32 -> Bt [768][256] bf16 (transposed)
__global__ __launch_bounds__(256) void k_convw(const float* __restrict__ w_qkv,
                                               u16* __restrict__ bt) {
  int i = blockIdx.x * 256 + threadIdx.x;  // 196608 total
  int k = i / 768, n = i % 768;
  bt[(size_t)n * 256 + k] = f2bf(w_qkv[i]);
}

// K3: reduce partials -> region mean, scores, top-4 (ties -> lower index)
__global__ __launch_bounds__(256) void k_topk(const float* __restrict__ partial,
                                              int* __restrict__ idx) {
  __shared__ float rs[NB * NW * NC];  // 64 KB
  int tid = threadIdx.x;
  for (int i = tid; i < NB * NW * NC; i += 256) {
    float s = 0.f;
    for (int t = 0; t < NT; ++t) s += partial[(size_t)t * NB * NW * NC + i];
    rs[i] = s * (1.0f / 1024.0f);
  }
  __syncthreads();
  if (tid < NB * NW) {
    int b = tid >> 5, w = tid & 31;
    const float scale = 0.17677669529663687f;  // 32^-0.5
    float sc[NW];
    for (int v = 0; v < NW; ++v) {
      float s = 0.f;
      const float* a = &rs[(b * NW + w) * NC];
      const float* bb = &rs[(b * NW + v) * NC];
      for (int c = 0; c < NC; ++c) s += a[c] * bb[c];
      sc[v] = s * scale;
    }
    for (int kk = 0; kk < NK; ++kk) {
      float best = -__builtin_inff(); int bi = 0;
      for (int v = 0; v < NW; ++v)
        if (sc[v] > best) { best = sc[v]; bi = v; }
      idx[(b * NW + w) * NK + kk] = bi;
      sc[bi] = -__builtin_inff();
    }
  }
}

// K4: MFMA GEMM: qkv[65536][768] = Xw[65536][256] @ w_qkv[256][768] + b_qkv,
// thresholded at 2.0 into spike bitmasks {q,k,v}b[token*8+h] bit d.
// 128x128 tile, BK=32 double-buffered, 4 waves x (4x4) 16x16x32 bf16 MFMA.
__global__ __launch_bounds__(256) void k_gemm(const float* __restrict__ x,
                                              const u16* __restrict__ bt,
                                              const float* __restrict__ b_qkv,
                                              u32* __restrict__ qb, u32* __restrict__ kb,
                                              u32* __restrict__ vb) {
  __shared__ __align__(16) u16 As[2][128 * 32];  // [row][k]
  __shared__ __align__(16) u16 Bs[2][128 * 32];  // [col][k]
  __shared__ u32 pack[128 * 4];

  const int tid = threadIdx.x;
  const int mtile = blockIdx.x;  // 0..511
  const int ntile = blockIdx.y;  // 0..5
  const int m0 = mtile * 128, n0 = ntile * 128;
  const int wave = tid >> 6, lane = tid & 63;
  const int wr = wave >> 1, wc = wave & 1;  // 2x2 waves of 64x64

  for (int i = tid; i < 128 * 4; i += 256) pack[i] = 0;

  const f32x4 vz = {0.f, 0.f, 0.f, 0.f};
  f32x4 acc[4][4];
#pragma unroll
  for (int m = 0; m < 4; ++m)
#pragma unroll
    for (int n = 0; n < 4; ++n) acc[m][n] = vz;

  auto stage = [&](int buf, int ks) {
    const int k0 = ks * 32;
    // A: 128 rows x 32 cols fp32 -> bf16 (1024 float4 over 256 threads)
#pragma unroll
    for (int p = 0; p < 4; ++p) {
      int idx = p * 256 + tid;
      int row = idx >> 3, c4 = idx & 7;
      int g = m0 + row;
      int s = g & 255, w = (g >> 8) & 31, tb = g >> 13;
      int b = tb & 1, t = tb >> 1;
      float4 v = *reinterpret_cast<const float4*>(&x[x_off(t, b, w, s, k0 + c4 * 4)]);
      u16* d = &As[buf][row * 32 + c4 * 4];
      d[0] = f2bf(v.x); d[1] = f2bf(v.y); d[2] = f2bf(v.z); d[3] = f2bf(v.w);
    }
    // B: 128 cols x 32 k bf16 (512 x 16B over 256 threads)
#pragma unroll
    for (int p = 0; p < 2; ++p) {
      int idx = p * 256 + tid;
      int row = idx >> 2, ch = idx & 3;
      u16x8 v = *reinterpret_cast<const u16x8*>(&bt[(size_t)(n0 + row) * 256 + k0 + ch * 8]);
      *reinterpret_cast<u16x8*>(&Bs[buf][row * 32 + ch * 8]) = v;
    }
  };

  stage(0, 0);
  __syncthreads();
#pragma unroll
  for (int ks = 0; ks < 8; ++ks) {
    const int buf = ks & 1;
    if (ks < 7) stage(buf ^ 1, ks + 1);
    bf16x8 afr[4], bfr[4];
#pragma unroll
    for (int m = 0; m < 4; ++m)
      afr[m] = *reinterpret_cast<const bf16x8*>(
          &As[buf][(wr * 64 + m * 16 + (lane & 15)) * 32 + (lane >> 4) * 8]);
#pragma unroll
    for (int n = 0; n < 4; ++n)
      bfr[n] = *reinterpret_cast<const bf16x8*>(
          &Bs[buf][(wc * 64 + n * 16 + (lane & 15)) * 32 + (lane >> 4) * 8]);
#pragma unroll
    for (int m = 0; m < 4; ++m)
#pragma unroll
      for (int n = 0; n < 4; ++n)
        acc[m][n] = __builtin_amdgcn_mfma_f32_16x16x32_bf16(afr[m], bfr[n], acc[m][n], 0, 0, 0);
    __syncthreads();
  }

  // epilogue: bias + threshold; spikes are ~never taken -> predicated LDS atomicOr
  float bias[4];
#pragma unroll
  for (int n = 0; n < 4; ++n) bias[n] = b_qkv[n0 + wc * 64 + n * 16 + (lane & 15)];
#pragma unroll
  for (int m = 0; m < 4; ++m)
#pragma unroll
    for (int n = 0; n < 4; ++n)
#pragma unroll
      for (int r = 0; r < 4; ++r) {
        float v = acc[m][n][r] + bias[n];
        if (v >= 2.0f) {
          int row = wr * 64 + m * 16 + (lane >> 4) * 4 + r;      // C/D: row=(lane>>4)*4+reg
          int colb = wc * 64 + n * 16 + (lane & 15);             //      col=lane&15
          atomicOr(&pack[row * 4 + (colb >> 5)], 1u << (colb & 31));
        }
      }
  __syncthreads();
  u32* dst = (ntile < 2) ? qb : (ntile < 4) ? kb : vb;  // BN=128 = 4 slot-words, never crosses q/k/v
  const int h0 = (ntile * 4) & 7;
  for (int i = tid; i < 128 * 4; i += 256) {
    int row = i >> 2, j = i & 3;
    dst[(size_t)(m0 + row) * NH + h0 + j] = pack[i];
  }
}

// K5: fused gather + linear attention + proj + window reverse.
__global__ __launch_bounds__(256) void k_attn(const u32* __restrict__ qb,
                                              const u32* __restrict__ kb,
                                              const u32* __restrict__ vb,
                                              const int* __restrict__ idx,
                                              const float* __restrict__ w_proj,
                                              const float* __restrict__ b_proj,
                                              float* __restrict__ out) {
  __shared__ u32 qs[NS * NH];
  __shared__ unsigned short kvc[NH * ND * ND];
  __shared__ u32 ksum[NH * ND];
  __shared__ float attnrow[NC];
  __shared__ size_t gbase[NK];
  __shared__ u32 flags[2];

  int blk = blockIdx.x;  // 256 = t*64 + b*32 + w
  int t = blk >> 6, b = (blk >> 5) & 1, w = blk & 31;
  int tid = threadIdx.x;
  if (tid < 2) flags[tid] = 0;
  if (tid < NK) {
    int wj = idx[(b * NW + w) * NK + tid];
    gbase[tid] = ((size_t)((t * NB + b) * NW + wj)) * NS * NH;
  }
  size_t qbase = ((size_t)((t * NB + b) * NW + w)) * NS * NH;
  u32 myq = 0;
  for (int i = tid; i < NS * NH; i += 256) { u32 u = qb[qbase + i]; qs[i] = u; myq |= u; }
  __syncthreads();
  u32 mykv = 0;
  for (int i = tid; i < NK * NS * NH; i += 256) {
    int j = i >> 11, r = i & 2047;
    u32 ku = kb[gbase[j] + r], vu = vb[gbase[j] + r];
    if (ku && vu) mykv = 1;
  }
  if (myq) atomicOr(&flags[0], 1u);
  if (mykv) atomicOr(&flags[1], 1u);
  __syncthreads();
  bool skip = (flags[0] == 0) || (flags[1] == 0);

  if (skip) {
    float bp = b_proj[tid];
    for (int s = 0; s < NS; ++s) out[x_off(t, b, w, s, tid)] = bp;
    return;
  }

  // exact integer slow path (only if spikes exist)
  {
    int h = tid >> 5, d = tid & 31;
    u32 cnt = 0;
    for (int n = 0; n < NK * NS; ++n)
      cnt += (kb[gbase[n >> 8] + (n & 255) * NH + h] >> d) & 1u;
    ksum[tid] = cnt;
  }
  for (int p = tid; p < NH * ND * ND; p += 256) {
    int h = p >> 10, d = (p >> 5) & 31, e = p & 31;
    u32 cnt = 0;
    for (int n = 0; n < NK * NS; ++n) {
      u32 ku = kb[gbase[n >> 8] + (n & 255) * NH + h];
      u32 vu = vb[gbase[n >> 8] + (n & 255) * NH + h];
      cnt += ((ku >> d) & (vu >> e)) & 1u;
    }
    kvc[p] = (unsigned short)cnt;
  }
  __syncthreads();
  int h = tid >> 5, e = tid & 31;
  float bpv = b_proj[tid];
  for (int s = 0; s < NS; ++s) {
    u32 qw = qs[s * NH + h];
    float num = 0.f, den = 0.f;
    for (int d = 0; d < ND; ++d) {
      if ((qw >> d) & 1u) {
        den += (float)ksum[h * ND + d];
        num += (float)kvc[h * ND * ND + d * ND + e];
      }
    }
    attnrow[tid] = num / (den + 1e-6f);
    __syncthreads();
    float acc = bpv;
    for (int c = 0; c < NC; ++c) acc += attnrow[c] * w_proj[c * NC + tid];
    out[x_off(t, b, w, s, tid)] = acc;
    __syncthreads();
  }
}

extern "C" void kernel_launch(void* const* d_in, const int* in_sizes, int n_in,
                              void* d_out, int out_size, void* d_ws, size_t ws_size,
                              hipStream_t stream) {
  const float* x      = (const float*)d_in[0];
  const float* w_qkv  = (const float*)d_in[1];
  const float* b_qkv  = (const float*)d_in[2];
  const float* w_proj = (const float*)d_in[3];
  const float* b_proj = (const float*)d_in[4];
  float* out = (float*)d_out;

  char* ws = (char*)d_ws;
  float* partial = (float*)ws;                    // 256 KB
  int* idx       = (int*)(ws + 0x40000);          // 1 KB
  u16* bt        = (u16*)(ws + 0x41000);          // 384 KB bf16 [768][256]
  u32* qb        = (u32*)(ws + 0x100000);         // 2 MB each
  u32* kb        = qb + (size_t)NT * NB * NW * NS * NH;
  u32* vb        = kb + (size_t)NT * NB * NW * NS * NH;

  k_region<<<NT * NB * NW, 256, 0, stream>>>(x, partial);
  k_convw<<<768, 256, 0, stream>>>(w_qkv, bt);
  k_topk<<<1, 256, 0, stream>>>(partial, idx);
  k_gemm<<<dim3(512, 6), 256, 0, stream>>>(x, bt, b_qkv, qb, kb, vb);
  k_attn<<<NT * NB * NW, 256, 0, stream>>>(qb, kb, vb, idx, w_proj, b_proj, out);
}

// Round 5
// 145.201 us; speedup vs baseline: 42.2104x; 1.5987x over previous
//
#include <hip/hip_runtime.h>
#include <hip/hip_bf16.h>
#include <stdint.h>

// BiLevelRoutingAttention (spiking LIF), T=4 B=2 L=8x32x32 C=256, fp32 I/O.
#define NT 4
#define NB 2
#define NW 32   // windows = 2*4*4
#define NS 256  // tokens/window = 4*8*8
#define NC 256
#define NH 8
#define ND 32
#define NK 4    // topk

typedef unsigned int u32;
typedef unsigned short u16;
typedef __attribute__((ext_vector_type(8))) short bf16x8;   // 8 bf16 (4 VGPRs)
typedef __attribute__((ext_vector_type(8))) unsigned short u16x8;
typedef __attribute__((ext_vector_type(4))) float f32x4;

// window/space mapping:
//   w = wt*16 + wh*4 + ww ; s = it*64 + ih*8 + iw
//   Lt = wt*4+it, Lh = wh*8+ih, Lw = ww*8+iw
__device__ __forceinline__ size_t x_off(int t, int b, int w, int s, int c) {
  int wt = w >> 4, wh = (w >> 2) & 3, ww = w & 3;
  int it = s >> 6, ih = (s >> 3) & 7, iw = s & 7;
  return ((((size_t)(t * NB + b) * 8 + (wt * 4 + it)) * 32 + (wh * 8 + ih)) * 32 + (ww * 8 + iw)) * NC + c;
}

// fp32 -> bf16 round-to-nearest-even (self-contained)
__device__ __forceinline__ u16 f2bf(float f) {
  union { float f; u32 i; } u; u.f = f;
  u32 r = (u.i + 0x7FFFu + ((u.i >> 16) & 1u)) >> 16;
  return (u16)r;
}

// K1: partial sums over 64-token s-chunks:
// partial[(((t*NB+b)*NW+w)*4+chunk)*NC + c] = sum_{s in chunk} x
__global__ __launch_bounds__(256) void k_region(const float* __restrict__ x,
                                                float* __restrict__ partial) {
  int blk = blockIdx.x;  // 1024
  int chunk = blk & 3, w = (blk >> 2) & 31, b = (blk >> 7) & 1, t = blk >> 8;
  int c = threadIdx.x;
  float sum = 0.f;
  int s0 = chunk * 64;
  for (int s = s0; s < s0 + 64; ++s) sum += x[x_off(t, b, w, s, c)];
  partial[(size_t)blk * NC + c] = sum;
}

// K2: w_qkv [256][768] fp32 -> Bt [768][256] bf16 (transposed)
__global__ __launch_bounds__(256) void k_convw(const float* __restrict__ w_qkv,
                                               u16* __restrict__ bt) {
  int i = blockIdx.x * 256 + threadIdx.x;  // 196608 total
  int k = i / 768, n = i % 768;
  bt[(size_t)n * 256 + k] = f2bf(w_qkv[i]);
}

// K3: per-(b,w) scores + top-4 (ties -> lower index, matching jax.lax.top_k)
__global__ __launch_bounds__(256) void k_scores(const float* __restrict__ partial,
                                                int* __restrict__ idx) {
  __shared__ float rs[NW][NC];   // 32 KB: region rows for this b
  __shared__ float scval[NW];
  int blk = blockIdx.x;          // 64 = b*32 + w
  int b = blk >> 5, w = blk & 31;
  int tid = threadIdx.x;
  // region[v][c] = mean over t(4) x chunk(4) partials
  for (int i = tid; i < NW * NC; i += 256) {
    int v = i >> 8, c = i & 255;
    float s = 0.f;
#pragma unroll
    for (int t = 0; t < NT; ++t)
#pragma unroll
      for (int ch = 0; ch < 4; ++ch)
        s += partial[(size_t)((((t * NB + b) * NW + v) * 4) + ch) * NC + c];
    rs[v][c] = s * (1.0f / 1024.0f);
  }
  __syncthreads();
  // 8 lanes per score; 32 scores
  int v = tid >> 3, l8 = tid & 7;
  float sum = 0.f;
  const float* a = rs[w];
  const float* bb = rs[v];
#pragma unroll
  for (int j = 0; j < 32; ++j) sum += a[l8 * 32 + j] * bb[l8 * 32 + j];
  sum += __shfl_xor(sum, 1);
  sum += __shfl_xor(sum, 2);
  sum += __shfl_xor(sum, 4);
  if (l8 == 0) scval[v] = sum * 0.17677669529663687f;  // 32^-0.5
  __syncthreads();
  if (tid == 0) {
    float sc[NW];
#pragma unroll
    for (int j = 0; j < NW; ++j) sc[j] = scval[j];
    for (int kk = 0; kk < NK; ++kk) {
      float best = -__builtin_inff(); int bi = 0;
      for (int j = 0; j < NW; ++j)
        if (sc[j] > best) { best = sc[j]; bi = j; }
      idx[(b * NW + w) * NK + kk] = bi;
      sc[bi] = -__builtin_inff();
    }
  }
}

// K4: MFMA GEMM: qkv[65536][768] = Xw[65536][256] @ w_qkv[256][768] + b_qkv,
// thresholded at 2.0 into spike bitmasks {q,k,v}b[token*8+h] bit d.
// 128x128 tile, BK=32 double-buffered, 4 waves x (4x4) 16x16x32 bf16 MFMA.
__global__ __launch_bounds__(256) void k_gemm(const float* __restrict__ x,
                                              const u16* __restrict__ bt,
                                              const float* __restrict__ b_qkv,
                                              u32* __restrict__ qb, u32* __restrict__ kb,
                                              u32* __restrict__ vb) {
  __shared__ __align__(16) u16 As[2][128 * 32];  // [row][k]
  __shared__ __align__(16) u16 Bs[2][128 * 32];  // [col][k]
  __shared__ u32 pack[128 * 4];

  const int tid = threadIdx.x;
  const int mtile = blockIdx.x;  // 0..511
  const int ntile = blockIdx.y;  // 0..5
  const int m0 = mtile * 128, n0 = ntile * 128;
  const int wave = tid >> 6, lane = tid & 63;
  const int wr = wave >> 1, wc = wave & 1;  // 2x2 waves of 64x64

  for (int i = tid; i < 128 * 4; i += 256) pack[i] = 0;

  const f32x4 vz = {0.f, 0.f, 0.f, 0.f};
  f32x4 acc[4][4];
#pragma unroll
  for (int m = 0; m < 4; ++m)
#pragma unroll
    for (int n = 0; n < 4; ++n) acc[m][n] = vz;

  auto stage = [&](int buf, int ks) {
    const int k0 = ks * 32;
    // A: 128 rows x 32 cols fp32 -> bf16 (1024 float4 over 256 threads)
#pragma unroll
    for (int p = 0; p < 4; ++p) {
      int idx = p * 256 + tid;
      int row = idx >> 3, c4 = idx & 7;
      int g = m0 + row;
      int s = g & 255, w = (g >> 8) & 31, tb = g >> 13;
      int b = tb & 1, t = tb >> 1;
      float4 v = *reinterpret_cast<const float4*>(&x[x_off(t, b, w, s, k0 + c4 * 4)]);
      u16* d = &As[buf][row * 32 + c4 * 4];
      d[0] = f2bf(v.x); d[1] = f2bf(v.y); d[2] = f2bf(v.z); d[3] = f2bf(v.w);
    }
    // B: 128 cols x 32 k bf16 (512 x 16B over 256 threads)
#pragma unroll
    for (int p = 0; p < 2; ++p) {
      int idx = p * 256 + tid;
      int row = idx >> 2, ch = idx & 3;
      u16x8 v = *reinterpret_cast<const u16x8*>(&bt[(size_t)(n0 + row) * 256 + k0 + ch * 8]);
      *reinterpret_cast<u16x8*>(&Bs[buf][row * 32 + ch * 8]) = v;
    }
  };

  stage(0, 0);
  __syncthreads();
#pragma unroll
  for (int ks = 0; ks < 8; ++ks) {
    const int buf = ks & 1;
    if (ks < 7) stage(buf ^ 1, ks + 1);
    bf16x8 afr[4], bfr[4];
#pragma unroll
    for (int m = 0; m < 4; ++m)
      afr[m] = *reinterpret_cast<const bf16x8*>(
          &As[buf][(wr * 64 + m * 16 + (lane & 15)) * 32 + (lane >> 4) * 8]);
#pragma unroll
    for (int n = 0; n < 4; ++n)
      bfr[n] = *reinterpret_cast<const bf16x8*>(
          &Bs[buf][(wc * 64 + n * 16 + (lane & 15)) * 32 + (lane >> 4) * 8]);
#pragma unroll
    for (int m = 0; m < 4; ++m)
#pragma unroll
      for (int n = 0; n < 4; ++n)
        acc[m][n] = __builtin_amdgcn_mfma_f32_16x16x32_bf16(afr[m], bfr[n], acc[m][n], 0, 0, 0);
    __syncthreads();
  }

  // epilogue: bias + threshold; spikes are ~never taken -> predicated LDS atomicOr
  float bias[4];
#pragma unroll
  for (int n = 0; n < 4; ++n) bias[n] = b_qkv[n0 + wc * 64 + n * 16 + (lane & 15)];
#pragma unroll
  for (int m = 0; m < 4; ++m)
#pragma unroll
    for (int n = 0; n < 4; ++n)
#pragma unroll
      for (int r = 0; r < 4; ++r) {
        float v = acc[m][n][r] + bias[n];
        if (v >= 2.0f) {
          int row = wr * 64 + m * 16 + (lane >> 4) * 4 + r;      // C/D: row=(lane>>4)*4+reg
          int colb = wc * 64 + n * 16 + (lane & 15);             //      col=lane&15
          atomicOr(&pack[row * 4 + (colb >> 5)], 1u << (colb & 31));
        }
      }
  __syncthreads();
  u32* dst = (ntile < 2) ? qb : (ntile < 4) ? kb : vb;  // BN=128 = 4 slot-words, never crosses q/k/v
  const int h0 = (ntile * 4) & 7;
  for (int i = tid; i < 128 * 4; i += 256) {
    int row = i >> 2, j = i & 3;
    dst[(size_t)(m0 + row) * NH + h0 + j] = pack[i];
  }
}

// K5: fused gather + linear attention + proj + window reverse.
__global__ __launch_bounds__(256) void k_attn(const u32* __restrict__ qb,
                                              const u32* __restrict__ kb,
                                              const u32* __restrict__ vb,
                                              const int* __restrict__ idx,
                                              const float* __restrict__ w_proj,
                                              const float* __restrict__ b_proj,
                                              float* __restrict__ out) {
  __shared__ u32 qs[NS * NH];
  __shared__ unsigned short kvc[NH * ND * ND];
  __shared__ u32 ksum[NH * ND];
  __shared__ float attnrow[NC];
  __shared__ size_t gbase[NK];
  __shared__ u32 flags[2];

  int blk = blockIdx.x;  // 256 = t*64 + b*32 + w
  int t = blk >> 6, b = (blk >> 5) & 1, w = blk & 31;
  int tid = threadIdx.x;
  if (tid < 2) flags[tid] = 0;
  if (tid < NK) {
    int wj = idx[(b * NW + w) * NK + tid];
    gbase[tid] = ((size_t)((t * NB + b) * NW + wj)) * NS * NH;
  }
  size_t qbase = ((size_t)((t * NB + b) * NW + w)) * NS * NH;
  u32 myq = 0;
  for (int i = tid; i < NS * NH; i += 256) { u32 u = qb[qbase + i]; qs[i] = u; myq |= u; }
  __syncthreads();
  u32 mykv = 0;
  for (int i = tid; i < NK * NS * NH; i += 256) {
    int j = i >> 11, r = i & 2047;
    u32 ku = kb[gbase[j] + r], vu = vb[gbase[j] + r];
    if (ku && vu) mykv = 1;
  }
  if (myq) atomicOr(&flags[0], 1u);
  if (mykv) atomicOr(&flags[1], 1u);
  __syncthreads();
  bool skip = (flags[0] == 0) || (flags[1] == 0);

  if (skip) {
    float bp = b_proj[tid];
    for (int s = 0; s < NS; ++s) out[x_off(t, b, w, s, tid)] = bp;
    return;
  }

  // exact integer slow path (only if spikes exist)
  {
    int h = tid >> 5, d = tid & 31;
    u32 cnt = 0;
    for (int n = 0; n < NK * NS; ++n)
      cnt += (kb[gbase[n >> 8] + (n & 255) * NH + h] >> d) & 1u;
    ksum[tid] = cnt;
  }
  for (int p = tid; p < NH * ND * ND; p += 256) {
    int h = p >> 10, d = (p >> 5) & 31, e = p & 31;
    u32 cnt = 0;
    for (int n = 0; n < NK * NS; ++n) {
      u32 ku = kb[gbase[n >> 8] + (n & 255) * NH + h];
      u32 vu = vb[gbase[n >> 8] + (n & 255) * NH + h];
      cnt += ((ku >> d) & (vu >> e)) & 1u;
    }
    kvc[p] = (unsigned short)cnt;
  }
  __syncthreads();
  int h = tid >> 5, e = tid & 31;
  float bpv = b_proj[tid];
  for (int s = 0; s < NS; ++s) {
    u32 qw = qs[s * NH + h];
    float num = 0.f, den = 0.f;
    for (int d = 0; d < ND; ++d) {
      if ((qw >> d) & 1u) {
        den += (float)ksum[h * ND + d];
        num += (float)kvc[h * ND * ND + d * ND + e];
      }
    }
    attnrow[tid] = num / (den + 1e-6f);
    __syncthreads();
    float acc = bpv;
    for (int c = 0; c < NC; ++c) acc += attnrow[c] * w_proj[c * NC + tid];
    out[x_off(t, b, w, s, tid)] = acc;
    __syncthreads();
  }
}

extern "C" void kernel_launch(void* const* d_in, const int* in_sizes, int n_in,
                              void* d_out, int out_size, void* d_ws, size_t ws_size,
                              hipStream_t stream) {
  const float* x      = (const float*)d_in[0];
  const float* w_qkv  = (const float*)d_in[1];
  const float* b_qkv  = (const float*)d_in[2];
  const float* w_proj = (const float*)d_in[3];
  const float* b_proj = (const float*)d_in[4];
  float* out = (float*)d_out;

  char* ws = (char*)d_ws;
  float* partial = (float*)ws;                    // 1 MB: [t][b][w][chunk][c]
  int* idx       = (int*)(ws + 0x100000);         // 1 KB
  u16* bt        = (u16*)(ws + 0x101000);         // 384 KB bf16 [768][256]
  u32* qb        = (u32*)(ws + 0x200000);         // 2 MB each
  u32* kb        = qb + (size_t)NT * NB * NW * NS * NH;
  u32* vb        = kb + (size_t)NT * NB * NW * NS * NH;

  k_region<<<NT * NB * NW * 4, 256, 0, stream>>>(x, partial);
  k_convw<<<768, 256, 0, stream>>>(w_qkv, bt);
  k_scores<<<NB * NW, 256, 0, stream>>>(partial, idx);
  k_gemm<<<dim3(512, 6), 256, 0, stream>>>(x, bt, b_qkv, qb, kb, vb);
  k_attn<<<NT * NB * NW, 256, 0, stream>>>(qb, kb, vb, idx, w_proj, b_proj, out);
}

// Round 6
// 113.704 us; speedup vs baseline: 53.9032x; 1.2770x over previous
//
#include <hip/hip_runtime.h>
#include <hip/hip_bf16.h>
#include <stdint.h>

// BiLevelRoutingAttention (spiking LIF), T=4 B=2 L=8x32x32 C=256, fp32 I/O.
#define NT 4
#define NB 2
#define NW 32   // windows = 2*4*4
#define NS 256  // tokens/window = 4*8*8
#define NC 256
#define NH 8
#define ND 32
#define NK 4    // topk

#define LDP 40  // padded LDS row stride in u16 (80 B): (5*row+slot)%8 -> conflict-free b128 reads

typedef unsigned int u32;
typedef unsigned short u16;
typedef __attribute__((ext_vector_type(8))) short bf16x8;   // 8 bf16 (4 VGPRs)
typedef __attribute__((ext_vector_type(8))) unsigned short u16x8;
typedef __attribute__((ext_vector_type(4))) float f32x4;

// window/space mapping:
//   w = wt*16 + wh*4 + ww ; s = it*64 + ih*8 + iw
//   Lt = wt*4+it, Lh = wh*8+ih, Lw = ww*8+iw
__device__ __forceinline__ size_t x_off(int t, int b, int w, int s, int c) {
  int wt = w >> 4, wh = (w >> 2) & 3, ww = w & 3;
  int it = s >> 6, ih = (s >> 3) & 7, iw = s & 7;
  return ((((size_t)(t * NB + b) * 8 + (wt * 4 + it)) * 32 + (wh * 8 + ih)) * 32 + (ww * 8 + iw)) * NC + c;
}

// fp32 -> bf16 round-to-nearest-even (self-contained)
__device__ __forceinline__ u16 f2bf(float f) {
  union { float f; u32 i; } u; u.f = f;
  u32 r = (u.i + 0x7FFFu + ((u.i >> 16) & 1u)) >> 16;
  return (u16)r;
}

// K1: gather+convert x -> Xw[65536][256] bf16 (GEMM row order), fused region partials.
// blk = ((t*NB+b)*NW+w)*4 + chunk ; 64 tokens per block.
__global__ __launch_bounds__(256) void k_convx(const float* __restrict__ x,
                                               u16* __restrict__ xw,
                                               float* __restrict__ partial) {
  __shared__ float sums[4][NC];  // per token-group column sums
  int blk = blockIdx.x;  // 1024
  int chunk = blk & 3, w = (blk >> 2) & 31, b = (blk >> 7) & 1, t = blk >> 8;
  int tid = threadIdx.x;
  int grp = tid >> 6, c4 = tid & 63;
  float4 acc = {0.f, 0.f, 0.f, 0.f};
#pragma unroll
  for (int iter = 0; iter < 16; ++iter) {
    int l = iter * 4 + grp;               // local token 0..63
    int s = chunk * 64 + l;
    float4 v = *reinterpret_cast<const float4*>(&x[x_off(t, b, w, s, c4 * 4)]);
    acc.x += v.x; acc.y += v.y; acc.z += v.z; acc.w += v.w;
    size_t g = (size_t)blk * 64 + l;      // GEMM row
    uint2 bf;
    bf.x = (u32)f2bf(v.x) | ((u32)f2bf(v.y) << 16);
    bf.y = (u32)f2bf(v.z) | ((u32)f2bf(v.w) << 16);
    *reinterpret_cast<uint2*>(&xw[g * NC + c4 * 4]) = bf;
  }
  sums[grp][c4 * 4 + 0] = acc.x;
  sums[grp][c4 * 4 + 1] = acc.y;
  sums[grp][c4 * 4 + 2] = acc.z;
  sums[grp][c4 * 4 + 3] = acc.w;
  __syncthreads();
  int c = tid;
  partial[(size_t)blk * NC + c] = sums[0][c] + sums[1][c] + sums[2][c] + sums[3][c];
}

// K2: w_qkv [256][768] fp32 -> Bt [768][256] bf16 (transposed)
__global__ __launch_bounds__(256) void k_convw(const float* __restrict__ w_qkv,
                                               u16* __restrict__ bt) {
  int i = blockIdx.x * 256 + threadIdx.x;  // 196608 total
  int k = i / 768, n = i % 768;
  bt[(size_t)n * 256 + k] = f2bf(w_qkv[i]);
}

// K3: per-(b,w) scores + top-4 (ties -> lower index, matching jax.lax.top_k)
__global__ __launch_bounds__(256) void k_scores(const float* __restrict__ partial,
                                                int* __restrict__ idx) {
  __shared__ float rs[NW][NC];   // 32 KB: region rows for this b
  __shared__ float scval[NW];
  int blk = blockIdx.x;          // 64 = b*32 + w
  int b = blk >> 5, w = blk & 31;
  int tid = threadIdx.x;
  for (int i = tid; i < NW * NC; i += 256) {
    int v = i >> 8, c = i & 255;
    float s = 0.f;
#pragma unroll
    for (int t = 0; t < NT; ++t)
#pragma unroll
      for (int ch = 0; ch < 4; ++ch)
        s += partial[(size_t)((((t * NB + b) * NW + v) * 4) + ch) * NC + c];
    rs[v][c] = s * (1.0f / 1024.0f);
  }
  __syncthreads();
  int v = tid >> 3, l8 = tid & 7;
  float sum = 0.f;
  const float* a = rs[w];
  const float* bb = rs[v];
#pragma unroll
  for (int j = 0; j < 32; ++j) sum += a[l8 * 32 + j] * bb[l8 * 32 + j];
  sum += __shfl_xor(sum, 1);
  sum += __shfl_xor(sum, 2);
  sum += __shfl_xor(sum, 4);
  if (l8 == 0) scval[v] = sum * 0.17677669529663687f;  // 32^-0.5
  __syncthreads();
  if (tid == 0) {
    float sc[NW];
#pragma unroll
    for (int j = 0; j < NW; ++j) sc[j] = scval[j];
    for (int kk = 0; kk < NK; ++kk) {
      float best = -__builtin_inff(); int bi = 0;
      for (int j = 0; j < NW; ++j)
        if (sc[j] > best) { best = sc[j]; bi = j; }
      idx[(b * NW + w) * NK + kk] = bi;
      sc[bi] = -__builtin_inff();
    }
  }
}

// K4: MFMA GEMM: qkv[65536][768] = Xw[65536][256] @ w_qkv[256][768] + b_qkv,
// thresholded at 2.0 into spike bitmasks {q,k,v}b[token*8+h] bit d.
// 128x128 tile, BK=32 double-buffered, 4 waves x (4x4) 16x16x32 bf16 MFMA.
__global__ __launch_bounds__(256) void k_gemm(const u16* __restrict__ xw,
                                              const u16* __restrict__ bt,
                                              const float* __restrict__ b_qkv,
                                              u32* __restrict__ qb, u32* __restrict__ kb,
                                              u32* __restrict__ vb) {
  __shared__ __align__(16) u16 As[2][128 * LDP];  // [row][k], padded
  __shared__ __align__(16) u16 Bs[2][128 * LDP];  // [col][k], padded
  __shared__ u32 pack[128 * 4];

  const int tid = threadIdx.x;
  const int mtile = blockIdx.x;  // 0..511
  const int ntile = blockIdx.y;  // 0..5
  const int m0 = mtile * 128, n0 = ntile * 128;
  const int wave = tid >> 6, lane = tid & 63;
  const int wr = wave >> 1, wc = wave & 1;  // 2x2 waves of 64x64

  for (int i = tid; i < 128 * 4; i += 256) pack[i] = 0;

  const f32x4 vz = {0.f, 0.f, 0.f, 0.f};
  f32x4 acc[4][4];
#pragma unroll
  for (int m = 0; m < 4; ++m)
#pragma unroll
    for (int n = 0; n < 4; ++n) acc[m][n] = vz;

  auto stage = [&](int buf, int ks) {
    const int k0 = ks * 32;
    // A and B: 128 rows x 32 k bf16 each (512 x 16B chunks over 256 threads, x2)
#pragma unroll
    for (int p = 0; p < 2; ++p) {
      int idx = p * 256 + tid;
      int row = idx >> 2, ch = idx & 3;
      u16x8 va = *reinterpret_cast<const u16x8*>(&xw[(size_t)(m0 + row) * 256 + k0 + ch * 8]);
      *reinterpret_cast<u16x8*>(&As[buf][row * LDP + ch * 8]) = va;
      u16x8 vbb = *reinterpret_cast<const u16x8*>(&bt[(size_t)(n0 + row) * 256 + k0 + ch * 8]);
      *reinterpret_cast<u16x8*>(&Bs[buf][row * LDP + ch * 8]) = vbb;
    }
  };

  stage(0, 0);
  __syncthreads();
#pragma unroll
  for (int ks = 0; ks < 8; ++ks) {
    const int buf = ks & 1;
    if (ks < 7) stage(buf ^ 1, ks + 1);
    bf16x8 afr[4], bfr[4];
#pragma unroll
    for (int m = 0; m < 4; ++m)
      afr[m] = *reinterpret_cast<const bf16x8*>(
          &As[buf][(wr * 64 + m * 16 + (lane & 15)) * LDP + (lane >> 4) * 8]);
#pragma unroll
    for (int n = 0; n < 4; ++n)
      bfr[n] = *reinterpret_cast<const bf16x8*>(
          &Bs[buf][(wc * 64 + n * 16 + (lane & 15)) * LDP + (lane >> 4) * 8]);
#pragma unroll
    for (int m = 0; m < 4; ++m)
#pragma unroll
      for (int n = 0; n < 4; ++n)
        acc[m][n] = __builtin_amdgcn_mfma_f32_16x16x32_bf16(afr[m], bfr[n], acc[m][n], 0, 0, 0);
    __syncthreads();
  }

  // epilogue: bias + threshold; spikes are ~never taken -> predicated LDS atomicOr
  float bias[4];
#pragma unroll
  for (int n = 0; n < 4; ++n) bias[n] = b_qkv[n0 + wc * 64 + n * 16 + (lane & 15)];
#pragma unroll
  for (int m = 0; m < 4; ++m)
#pragma unroll
    for (int n = 0; n < 4; ++n)
#pragma unroll
      for (int r = 0; r < 4; ++r) {
        float v = acc[m][n][r] + bias[n];
        if (v >= 2.0f) {
          int row = wr * 64 + m * 16 + (lane >> 4) * 4 + r;      // C/D: row=(lane>>4)*4+reg
          int colb = wc * 64 + n * 16 + (lane & 15);             //      col=lane&15
          atomicOr(&pack[row * 4 + (colb >> 5)], 1u << (colb & 31));
        }
      }
  __syncthreads();
  u32* dst = (ntile < 2) ? qb : (ntile < 4) ? kb : vb;  // BN=128 = 4 slot-words, never crosses q/k/v
  const int h0 = (ntile * 4) & 7;
  for (int i = tid; i < 128 * 4; i += 256) {
    int row = i >> 2, j = i & 3;
    dst[(size_t)(m0 + row) * NH + h0 + j] = pack[i];
  }
}

// K5: fused gather + linear attention + proj + window reverse.
__global__ __launch_bounds__(256) void k_attn(const u32* __restrict__ qb,
                                              const u32* __restrict__ kb,
                                              const u32* __restrict__ vb,
                                              const int* __restrict__ idx,
                                              const float* __restrict__ w_proj,
                                              const float* __restrict__ b_proj,
                                              float* __restrict__ out) {
  __shared__ u32 qs[NS * NH];
  __shared__ unsigned short kvc[NH * ND * ND];
  __shared__ u32 ksum[NH * ND];
  __shared__ float attnrow[NC];
  __shared__ size_t gbase[NK];
  __shared__ u32 flags[2];

  int blk = blockIdx.x;  // 256 = t*64 + b*32 + w
  int t = blk >> 6, b = (blk >> 5) & 1, w = blk & 31;
  int tid = threadIdx.x;
  if (tid < 2) flags[tid] = 0;
  if (tid < NK) {
    int wj = idx[(b * NW + w) * NK + tid];
    gbase[tid] = ((size_t)((t * NB + b) * NW + wj)) * NS * NH;
  }
  size_t qbase = ((size_t)((t * NB + b) * NW + w)) * NS * NH;
  u32 myq = 0;
  for (int i = tid; i < NS * NH; i += 256) { u32 u = qb[qbase + i]; qs[i] = u; myq |= u; }
  __syncthreads();
  u32 mykv = 0;
  for (int i = tid; i < NK * NS * NH; i += 256) {
    int j = i >> 11, r = i & 2047;
    u32 ku = kb[gbase[j] + r], vu = vb[gbase[j] + r];
    if (ku && vu) mykv = 1;
  }
  if (myq) atomicOr(&flags[0], 1u);
  if (mykv) atomicOr(&flags[1], 1u);
  __syncthreads();
  bool skip = (flags[0] == 0) || (flags[1] == 0);

  if (skip) {
    float bp = b_proj[tid];
    for (int s = 0; s < NS; ++s) out[x_off(t, b, w, s, tid)] = bp;
    return;
  }

  // exact integer slow path (only if spikes exist)
  {
    int h = tid >> 5, d = tid & 31;
    u32 cnt = 0;
    for (int n = 0; n < NK * NS; ++n)
      cnt += (kb[gbase[n >> 8] + (n & 255) * NH + h] >> d) & 1u;
    ksum[tid] = cnt;
  }
  for (int p = tid; p < NH * ND * ND; p += 256) {
    int h = p >> 10, d = (p >> 5) & 31, e = p & 31;
    u32 cnt = 0;
    for (int n = 0; n < NK * NS; ++n) {
      u32 ku = kb[gbase[n >> 8] + (n & 255) * NH + h];
      u32 vu = vb[gbase[n >> 8] + (n & 255) * NH + h];
      cnt += ((ku >> d) & (vu >> e)) & 1u;
    }
    kvc[p] = (unsigned short)cnt;
  }
  __syncthreads();
  int h = tid >> 5, e = tid & 31;
  float bpv = b_proj[tid];
  for (int s = 0; s < NS; ++s) {
    u32 qw = qs[s * NH + h];
    float num = 0.f, den = 0.f;
    for (int d = 0; d < ND; ++d) {
      if ((qw >> d) & 1u) {
        den += (float)ksum[h * ND + d];
        num += (float)kvc[h * ND * ND + d * ND + e];
      }
    }
    attnrow[tid] = num / (den + 1e-6f);
    __syncthreads();
    float acc = bpv;
    for (int c = 0; c < NC; ++c) acc += attnrow[c] * w_proj[c * NC + tid];
    out[x_off(t, b, w, s, tid)] = acc;
    __syncthreads();
  }
}

extern "C" void kernel_launch(void* const* d_in, const int* in_sizes, int n_in,
                              void* d_out, int out_size, void* d_ws, size_t ws_size,
                              hipStream_t stream) {
  const float* x      = (const float*)d_in[0];
  const float* w_qkv  = (const float*)d_in[1];
  const float* b_qkv  = (const float*)d_in[2];
  const float* w_proj = (const float*)d_in[3];
  const float* b_proj = (const float*)d_in[4];
  float* out = (float*)d_out;

  char* ws = (char*)d_ws;
  float* partial = (float*)ws;                    // 1 MB: [t][b][w][chunk][c]
  int* idx       = (int*)(ws + 0x100000);         // 1 KB
  u16* bt        = (u16*)(ws + 0x101000);         // 384 KB bf16 [768][256]
  u32* qb        = (u32*)(ws + 0x200000);         // 2 MB each
  u32* kb        = qb + (size_t)NT * NB * NW * NS * NH;
  u32* vb        = kb + (size_t)NT * NB * NW * NS * NH;
  u16* xw        = (u16*)(ws + 0x800000);         // 32 MB bf16 [65536][256]

  k_convx<<<NT * NB * NW * 4, 256, 0, stream>>>(x, xw, partial);
  k_convw<<<768, 256, 0, stream>>>(w_qkv, bt);
  k_scores<<<NB * NW, 256, 0, stream>>>(partial, idx);
  k_gemm<<<dim3(512, 6), 256, 0, stream>>>(xw, bt, b_qkv, qb, kb, vb);
  k_attn<<<NT * NB * NW, 256, 0, stream>>>(qb, kb, vb, idx, w_proj, b_proj, out);
}